// Round 1
// baseline (1125.282 us; speedup 1.0000x reference)
//
#include <hip/hip_runtime.h>

// min_dist[b] = sqrt(max(2 - 2*max_m dot(xhat_b, y_m), 1e-12))  (unit vectors)
// B=1024 queries, M=262144 bank rows, D=512.
//
// Restructure vs previous version:
//  - 1024 WGs x 8 waves; WG = 512 bank rows x 512 query cols (vbid: rowgroup=vbid>>1, half=vbid&1)
//  - 32x32x16 bf16 MFMA, per-wave tile 128 rows x 64 cols (acc = 8 x f32x16 = 128 VGPR)
//  - K pipelined in panels of 256 (128 rows x 256 k), 2 x 64KB LDS double-buffer,
//    one __syncthreads per panel, T14 split staging (issue loads early, cvt+ds_write late)
//  - LDS layout: 16B line per (kg=k/8, row), line = kg*128 + (row ^ kg)  -> conflict-free
//    for both staging ds_write_b64 and A-frag ds_read_b128
//  - queries pre-packed in B-fragment order -> 1KB coalesced wave loads, L2-resident
//  - per-wave register running max -> int-keyed atomicMax per column

#define DIM        512
#define B_Q        1024
#define M_BANK     262144
#define NWG        1024
#define ROWS_PER_WG 512
#define CHUNK_ROWS 128
#define NPANELS    8          // 4 chunks * 2 k-halves
#define LDS_USHORT 32768      // 64 KB per buffer

typedef __attribute__((ext_vector_type(8))) short short8;
typedef __attribute__((ext_vector_type(16))) float f32x16;

__device__ inline unsigned short f2bf(float f) {
  union { float f; unsigned u; } x; x.f = f;
  unsigned r = x.u + 0x7FFFu + ((x.u >> 16) & 1u);   // RNE
  return (unsigned short)(r >> 16);
}

__device__ inline int fkey(float f) {        // monotone float -> signed-int key
  int i = __float_as_int(f);
  return i < 0 ? (i ^ 0x7fffffff) : i;
}

__device__ inline f32x16 zero16() {
  f32x16 z = {0.f,0.f,0.f,0.f,0.f,0.f,0.f,0.f,0.f,0.f,0.f,0.f,0.f,0.f,0.f,0.f};
  return z;
}

// ---------- Kernel 1: normalize queries, pack bf16 in B-fragment order, init gmax ----------
// Packing: element (c,k) -> line = ((c>>5)*32 + (k>>4))*64 + ((k>>3)&1)*32 + (c&31), j=k&7
// so a wave B-frag load for (colblock, ks) is 64 consecutive 16B lanes (1KB coalesced).
__global__ void normq_kernel(const float* __restrict__ X, unsigned short* __restrict__ Qn2,
                             int* __restrict__ gmax) {
  const int b = blockIdx.x;      // query row
  const int lane = threadIdx.x;  // 64; lane handles k = lane*8 .. +7
  const float4* row = (const float4*)(X + (size_t)b * DIM);
  float4 v0 = row[lane * 2];
  float4 v1 = row[lane * 2 + 1];
  float ss = v0.x*v0.x + v0.y*v0.y + v0.z*v0.z + v0.w*v0.w
           + v1.x*v1.x + v1.y*v1.y + v1.z*v1.z + v1.w*v1.w;
  #pragma unroll
  for (int o = 32; o >= 1; o >>= 1) ss += __shfl_xor(ss, o);
  const float inv = 1.0f / sqrtf(ss);
  const int line = ((b >> 5) * 32 + (lane >> 1)) * 64 + (lane & 1) * 32 + (b & 31);
  short8 o;
  o[0] = (short)f2bf(v0.x*inv); o[1] = (short)f2bf(v0.y*inv);
  o[2] = (short)f2bf(v0.z*inv); o[3] = (short)f2bf(v0.w*inv);
  o[4] = (short)f2bf(v1.x*inv); o[5] = (short)f2bf(v1.y*inv);
  o[6] = (short)f2bf(v1.z*inv); o[7] = (short)f2bf(v1.w*inv);
  *(short8*)(Qn2 + (size_t)line * 8) = o;
  if (lane == 0) gmax[b] = (int)0xBFFFFFFF;   // fkey(-2.0f)
}

// ---------- staging helpers (panel = 128 rows x 256 k fp32, 8192 float4) ----------
// batch half64 in {0,1}: rows half64*64..+63. Global: lane-contiguous 1KB/wave.
__device__ inline void stage_issue(const float4* __restrict__ src, int half64, int tid, float4* v) {
  #pragma unroll
  for (int i = 0; i < 8; ++i) {
    const int f4 = half64 * 4096 + i * 512 + tid;
    const int r  = f4 >> 6;          // panel row
    const int c4 = f4 & 63;          // float4 col within 256-k panel
    v[i] = src[(size_t)r * 128 + c4];
  }
}
__device__ inline void stage_write(unsigned short* __restrict__ dst, int half64, int tid, const float4* v) {
  const int lane = tid & 63;
  const int kg   = lane >> 1;          // k-group = (lane*4)/8
  const int sub  = (lane & 1) * 4;     // ushort offset within 16B line
  #pragma unroll
  for (int i = 0; i < 8; ++i) {
    const int r  = half64 * 64 + i * 8 + (tid >> 6);
    const int ln = kg * 128 + (r ^ kg);            // XOR swizzle
    ushort4 o = make_ushort4(f2bf(v[i].x), f2bf(v[i].y), f2bf(v[i].z), f2bf(v[i].w));
    *(ushort4*)(dst + ln * 8 + sub) = o;
  }
}

// One K-step (k=16): 4 A-frags (LDS) x 2 B-frags (global) -> 8 MFMA
#define KSTEP(ks)                                                                 \
  {                                                                               \
    const int kg_ = 2 * (ks) + hi;                                                \
    const unsigned short* ab_ = lb + kg_ * 1024 + ((lo ^ kg_) << 3);              \
    short8 a0_ = *(const short8*)(ab_);                                           \
    short8 a1_ = *(const short8*)(ab_ + 256);                                     \
    short8 a2_ = *(const short8*)(ab_ + 512);                                     \
    short8 a3_ = *(const short8*)(ab_ + 768);                                     \
    short8 b0_ = *(const short8*)(q0 + (ks) * 512);                               \
    short8 b1_ = *(const short8*)(q1 + (ks) * 512);                               \
    acc00 = __builtin_amdgcn_mfma_f32_32x32x16_bf16(a0_, b0_, acc00, 0, 0, 0);    \
    acc10 = __builtin_amdgcn_mfma_f32_32x32x16_bf16(a1_, b0_, acc10, 0, 0, 0);    \
    acc20 = __builtin_amdgcn_mfma_f32_32x32x16_bf16(a2_, b0_, acc20, 0, 0, 0);    \
    acc30 = __builtin_amdgcn_mfma_f32_32x32x16_bf16(a3_, b0_, acc30, 0, 0, 0);    \
    acc01 = __builtin_amdgcn_mfma_f32_32x32x16_bf16(a0_, b1_, acc01, 0, 0, 0);    \
    acc11 = __builtin_amdgcn_mfma_f32_32x32x16_bf16(a1_, b1_, acc11, 0, 0, 0);    \
    acc21 = __builtin_amdgcn_mfma_f32_32x32x16_bf16(a2_, b1_, acc21, 0, 0, 0);    \
    acc31 = __builtin_amdgcn_mfma_f32_32x32x16_bf16(a3_, b1_, acc31, 0, 0, 0);    \
  }

#define RMAX16(A, M) { _Pragma("unroll") for (int r_ = 0; r_ < 16; ++r_) M = fmaxf(M, A[r_]); A = zero16(); }

// ---------- Kernel 2: main GEMM + row-max ----------
__global__ __launch_bounds__(512, 2)
void patch_main(const float* __restrict__ bank, const unsigned short* __restrict__ Qn2,
                int* __restrict__ gmax) {
  __shared__ __attribute__((aligned(16))) unsigned short lds0[LDS_USHORT];
  __shared__ __attribute__((aligned(16))) unsigned short lds1[LDS_USHORT];

  const int tid  = threadIdx.x;
  const int lane = tid & 63;
  const int w    = tid >> 6;       // wave 0..7
  const int lo   = lane & 31;
  const int hi   = lane >> 5;

  // XCD-chunked swizzle: pair (vbid 2k, 2k+1) lands on the same XCD (bids 8 apart)
  const int bid  = blockIdx.x;
  const int vbid = (bid & 7) * 128 + (bid >> 3);
  const int g    = vbid >> 1;      // rowgroup 0..511
  const int h    = vbid & 1;       // query half

  const float4* bankF4 = (const float4*)bank;
  const size_t rowbase = (size_t)g * ROWS_PER_WG;

  f32x16 acc00 = zero16(), acc10 = zero16(), acc20 = zero16(), acc30 = zero16();
  f32x16 acc01 = zero16(), acc11 = zero16(), acc21 = zero16(), acc31 = zero16();
  float rmax0 = -2.0f, rmax1 = -2.0f;

  // B base: colblock cb0 = h*16 + w*2 (wave-exclusive 64 cols)
  const unsigned short* qb = Qn2 + (size_t)(h * 16 + w * 2) * 16384 + (size_t)lane * 8;

  // prologue: stage panel 0 (chunk 0, k-half 0) into lds0
  {
    const float4* src = bankF4 + rowbase * 128;
    float4 v[8];
    stage_issue(src, 0, tid, v);
    stage_write(lds0, 0, tid, v);
    stage_issue(src, 1, tid, v);
    stage_write(lds0, 1, tid, v);
  }
  __syncthreads();

  #pragma unroll 1
  for (int p = 0; p < NPANELS; ++p) {
    const unsigned short* lb = (p & 1) ? lds1 : lds0;
    unsigned short* nxt      = (p & 1) ? lds0 : lds1;
    const float4* nsrc = nullptr;
    if (p + 1 < NPANELS) {
      const int pn = p + 1;
      nsrc = bankF4 + (rowbase + (size_t)(pn >> 1) * CHUNK_ROWS) * 128 + (pn & 1) * 64;
    }
    const unsigned short* q0 = qb + (p & 1) * 8192;   // k-half select (16 ks * 512)
    const unsigned short* q1 = q0 + 16384;            // cb0+1

    float4 v[8];
    if (nsrc) stage_issue(nsrc, 0, tid, v);           // batch0 in flight under compute

    #pragma unroll
    for (int ks = 0; ks < 8; ++ks) KSTEP(ks)

    if (nsrc) { stage_write(nxt, 0, tid, v); stage_issue(nsrc, 1, tid, v); }

    #pragma unroll
    for (int ks = 8; ks < 16; ++ks) KSTEP(ks)

    if (nsrc) stage_write(nxt, 1, tid, v);

    if (p & 1) {   // chunk complete: fold acc into running max, re-zero
      float mx0 = -2.0f, mx1 = -2.0f;
      RMAX16(acc00, mx0) RMAX16(acc10, mx0) RMAX16(acc20, mx0) RMAX16(acc30, mx0)
      RMAX16(acc01, mx1) RMAX16(acc11, mx1) RMAX16(acc21, mx1) RMAX16(acc31, mx1)
      mx0 = fmaxf(mx0, __shfl_xor(mx0, 32));
      mx1 = fmaxf(mx1, __shfl_xor(mx1, 32));
      rmax0 = fmaxf(rmax0, mx0);
      rmax1 = fmaxf(rmax1, mx1);
    }
    __syncthreads();
  }

  // C/D: col = lane&31 (query). Wave-exclusive cols; one atomic per col.
  if (hi == 0) {
    const int col = h * 512 + w * 64 + lo;
    atomicMax(&gmax[col],      fkey(rmax0));
    atomicMax(&gmax[col + 32], fkey(rmax1));
  }
}

// ---------- Kernel 3: key -> distance ----------
__global__ void finalize_kernel(const int* __restrict__ gmax, float* __restrict__ out) {
  const int i = blockIdx.x * 256 + threadIdx.x;
  int k = gmax[i];
  k = k < 0 ? (k ^ 0x7fffffff) : k;
  const float m = __int_as_float(k);
  out[i] = sqrtf(fmaxf(2.0f - 2.0f * m, 1e-12f));
}

extern "C" void kernel_launch(void* const* d_in, const int* in_sizes, int n_in,
                              void* d_out, int out_size, void* d_ws, size_t ws_size,
                              hipStream_t stream) {
  const float* feats = (const float*)d_in[0];   // [1024, 512] fp32
  const float* bank  = (const float*)d_in[1];   // [262144, 512] fp32, pre-normalized
  float* out = (float*)d_out;                   // [1024] fp32

  unsigned short* Qn2 = (unsigned short*)d_ws;                      // 1 MB packed bf16 queries
  int* gmax = (int*)((char*)d_ws + (size_t)B_Q * DIM * 2);          // 4 KB keyed maxes

  normq_kernel<<<B_Q, 64, 0, stream>>>(feats, Qn2, gmax);
  patch_main<<<NWG, 512, 0, stream>>>(bank, Qn2, gmax);
  finalize_kernel<<<B_Q / 256, 256, 0, stream>>>(gmax, out);
}